// Round 13
// baseline (258.244 us; speedup 1.0000x reference)
//
#include <hip/hip_runtime.h>

typedef __bf16 bf16;
typedef __bf16 bf16x8 __attribute__((ext_vector_type(8)));
typedef float  f32x4  __attribute__((ext_vector_type(4)));

#define MFMA(a, b, c) __builtin_amdgcn_mfma_f32_16x16x32_bf16((a), (b), (c), 0, 0, 0)
#define LOG2E 1.4426950408889634f

__device__ __forceinline__ void gload16(const bf16* g, bf16* l) {
  __builtin_amdgcn_global_load_lds(
      (const __attribute__((address_space(1))) unsigned int*)g,
      (__attribute__((address_space(3))) unsigned int*)l, 16, 0, 0);
}

// fused "all my loads drained + workgroup barrier" — single asm block with
// memory clobber so no memory op can be scheduled between the wait and the
// barrier.
__device__ __forceinline__ void wait0_barrier() {
  asm volatile("s_waitcnt vmcnt(0)\n\ts_barrier" ::: "memory");
  __builtin_amdgcn_sched_barrier(0);
}

// fast GELU: x * e/(e+1), e = exp2(2*log2e*(0.79788456x + 0.0356774x^3))
__device__ __forceinline__ float gelu_f(float v) {
  float u = v * (0.7978845608f + 0.0356774081f * v * v);
  float t2 = fminf(u * (2.f * LOG2E), 126.f);
  float e = __builtin_amdgcn_exp2f(t2);
  return v * e * __builtin_amdgcn_rcpf(e + 1.f);
}

// ---------------- fused f32 -> bf16 convert for x + 4 weight tensors
__global__ __launch_bounds__(256)
void f2b_all_k(const float* __restrict__ x, const float* __restrict__ qkvw,
               const float* __restrict__ pw, const float* __restrict__ f1w,
               const float* __restrict__ f2w,
               bf16* __restrict__ xb, bf16* __restrict__ qkvwb,
               bf16* __restrict__ pwb, bf16* __restrict__ f1wb,
               bf16* __restrict__ f2wb)
{
  int i = blockIdx.x * 256 + threadIdx.x;   // 8-elem chunk index
  const float* in; bf16* out; int base;
  if      (i < 1048576) { in = x;    out = xb;    base = 0; }
  else if (i < 1146880) { in = qkvw; out = qkvwb; base = 1048576; }
  else if (i < 1179648) { in = pw;   out = pwb;   base = 1146880; }
  else if (i < 1310720) { in = f1w;  out = f1wb;  base = 1179648; }
  else if (i < 1441792) { in = f2w;  out = f2wb;  base = 1310720; }
  else return;
  size_t j = (size_t)(i - base) * 8;
  f32x4 a = *(const f32x4*)(in + j);
  f32x4 b = *(const f32x4*)(in + j + 4);
  bf16x8 o;
#pragma unroll
  for (int k = 0; k < 4; ++k) { o[k] = (bf16)a[k]; o[4 + k] = (bf16)b[k]; }
  *(bf16x8*)(out + j) = o;
}

// shifted-window token t = w*256+n  ->  natural token index (b*4096 + gh*64 + gw)
__device__ __forceinline__ int row_map(int t) {
  int w = t >> 8, n = t & 255;
  int b = w >> 4, wi = w & 15;
  int gh = (((wi >> 2) << 4) + (n >> 4) + 8) & 63;
  int gw = (((wi & 3) << 4) + (n & 15) + 8) & 63;
  return (b << 12) + (gh << 6) + gw;
}

// ---------------- GEMM v3c: BM=256 x BN tile, BK=64, 512 thr (8 waves 2Mx4N),
// wave tile 128 x BN/4. Sync skeleton: stage(t+1) at tile top, compute(t),
// ONE fused vmcnt(0)+barrier per tile. Quadrant sub-phases, setprio'd MFMA.
// XOR-swizzled LDS (pre-swizzled global source, linear dest, swizzled read).
// BITER FIX (r11/r12 NaN): chunks are 16 BYTES = 8 bf16 -> B tile needs
// BN*8/512 = BN/64 iters (4 for BN=256, 2 for BN=128).
// MODE 0: QKV  (A row-gather via row_map, bias=concat(qb,0,vb))   BN=256
// MODE 1: PROJ (bias, out rows scattered via row_map)             BN=128
// MODE 2: FC1  (bias + fast GELU, out split h0/h1 by col half)    BN=256
// MODE 3: FC2  (bias, A split h0/h1 by k half, K=2048)            BN=128
template<int MODE, int BN>
__global__ __launch_bounds__(512, 2)
void gemm3_k(const bf16* __restrict__ A0, const bf16* __restrict__ A1,
             const bf16* __restrict__ W,
             const float* __restrict__ b0, const float* __restrict__ b1,
             bf16* __restrict__ out0, bf16* __restrict__ out1,
             int K, int lda, int ldw, int ldc)
{
  constexpr int BITER = BN / 64;                 // B stage iters: 4 (BN256) / 2 (BN128)
  constexpr int NFR   = BN / 64;                 // n-frags per wave: 4 / 2
  constexpr int NFRQ  = BN / 128;                // n-frags per quadrant: 2 / 1
  __shared__ __align__(16) bf16 As[2][256 * 64]; // 64 KB
  __shared__ __align__(16) bf16 Bs[2][BN * 64];  // 64/32 KB
  const int tid  = threadIdx.x;
  const int lane = tid & 63;
  const int wave = tid >> 6;
  const int wm = wave >> 2, wn = wave & 3;       // 2 x 4 waves
  const int fr = lane & 15, fq = lane >> 4;
  const int m0 = blockIdx.x * 256, n0 = blockIdx.y * BN;

  f32x4 acc[8][NFR] = {};

  auto stage = [&](int buf, int t) {
    const int kb = t << 6;
#pragma unroll
    for (int i = 0; i < 4; ++i) {                // A: 256 rows x 8 chunks = 2048
      int c = tid + i * 512;
      int row = c >> 3, sl = c & 7;
      int kk = ((sl ^ (row & 7)) << 3);
      int arow = m0 + row;
      if (MODE == 0) arow = row_map(arow);
      const bf16* ap;
      if (MODE == 3) {
        const bf16* Ab = (kb < 1024) ? A0 : A1;
        ap = Ab + (size_t)arow * lda + (kb & 1023) + kk;
      } else {
        ap = A0 + (size_t)arow * lda + kb + kk;
      }
      gload16(ap, &As[buf][c * 8]);
    }
#pragma unroll
    for (int i = 0; i < BITER; ++i) {            // B: BN rows x 8 chunks
      int c = tid + i * 512;
      int row = c >> 3, sl = c & 7;
      int kk = ((sl ^ (row & 7)) << 3);
      gload16(W + (size_t)(n0 + row) * ldw + kb + kk, &Bs[buf][c * 8]);
    }
  };

  const int nt = K >> 6;
  stage(0, 0);
  wait0_barrier();                               // tile 0 in LDS for all waves
  for (int t = 0; t < nt; ++t) {
    if (t + 1 < nt) stage((t + 1) & 1, t + 1);   // flies over this tile's MFMA
    const bf16* as = As[t & 1];
    const bf16* bs = Bs[t & 1];
#pragma unroll
    for (int q = 0; q < 4; ++q) {  // quadrant sub-phase: qm=q>>1, qn=q&1
      const int qm = q >> 1, qn = q & 1;
      bf16x8 aF[4][2], bF[NFRQ][2];
#pragma unroll
      for (int m2 = 0; m2 < 4; ++m2)
#pragma unroll
        for (int ks = 0; ks < 2; ++ks) {
          int row = wm * 128 + qm * 64 + m2 * 16 + fr;
          aF[m2][ks] = *(const bf16x8*)&as[row * 64 + (((ks * 4 + fq) ^ (fr & 7)) << 3)];
        }
#pragma unroll
      for (int n2 = 0; n2 < NFRQ; ++n2)
#pragma unroll
        for (int ks = 0; ks < 2; ++ks) {
          int brow = wn * (BN / 4) + qn * (BN / 8) + n2 * 16 + fr;
          bF[n2][ks] = *(const bf16x8*)&bs[brow * 64 + (((ks * 4 + fq) ^ (fr & 7)) << 3)];
        }
      __builtin_amdgcn_s_setprio(1);
#pragma unroll
      for (int m2 = 0; m2 < 4; ++m2)
#pragma unroll
        for (int n2 = 0; n2 < NFRQ; ++n2)
#pragma unroll
          for (int ks = 0; ks < 2; ++ks)
            acc[qm * 4 + m2][qn * NFRQ + n2] =
                MFMA(aF[m2][ks], bF[n2][ks], acc[qm * 4 + m2][qn * NFRQ + n2]);
      __builtin_amdgcn_s_setprio(0);
    }
    if (t + 1 < nt) wait0_barrier();  // next tile landed AND all reads done
  }

#pragma unroll
  for (int mi = 0; mi < 8; ++mi) {
#pragma unroll
    for (int ni = 0; ni < NFR; ++ni) {
      int colb = n0 + wn * (BN / 4) + ni * 16 + fr;
      float badd;
      if (MODE == 0)
        badd = (colb < 512) ? b0[colb] : (colb < 1024 ? 0.f : b1[colb - 1024]);
      else
        badd = b0[colb];
#pragma unroll
      for (int r = 0; r < 4; ++r) {
        int rowb = m0 + wm * 128 + mi * 16 + fq * 4 + r;
        float v = acc[mi][ni][r] + badd;
        if (MODE == 0) out0[(size_t)rowb * ldc + colb] = (bf16)v;
        if (MODE == 1) out0[(size_t)row_map(rowb) * ldc + colb] = (bf16)v;
        if (MODE == 2) {
          v = gelu_f(v);
          bf16* ob = (colb < 1024) ? out0 : out1;
          ob[(size_t)rowb * 1024 + (colb & 1023)] = (bf16)v;
        }
        if (MODE == 3) out0[(size_t)rowb * ldc + colb] = (bf16)v;
      }
    }
  }
}

// ---------------- CPB MLP: btab[q][16], q = (dr+15)*31 + (dc+15)
__device__ __forceinline__ float cpb_coord(int r) {
  float t = (float)r * (8.0f / 15.0f);
  float v = log2f(fabsf(t) + 1.0f) * (1.0f / 3.0f);
  return (t < 0.0f) ? -v : v;
}

__global__ __launch_bounds__(64)
void cpb_tbl_k(const float* __restrict__ w1, const float* __restrict__ b1,
               const float* __restrict__ w2, float* __restrict__ btab)
{
  const int q = blockIdx.x;           // 0..960
  const int lane = threadIdx.x;       // 64
  const float t0 = cpb_coord(q / 31 - 15);
  const float t1 = cpb_coord(q % 31 - 15);
  float part[16];
#pragma unroll
  for (int o = 0; o < 16; ++o) part[o] = 0.f;
  for (int jj = 0; jj < 8; ++jj) {
    int j = lane * 8 + jj;
    float hv = t0 * w1[j * 2] + t1 * w1[j * 2 + 1] + b1[j];
    hv = fmaxf(hv, 0.f);
#pragma unroll
    for (int o = 0; o < 16; ++o) part[o] += hv * w2[o * 512 + j];
  }
#pragma unroll
  for (int o = 0; o < 16; ++o) {
#pragma unroll
    for (int d = 1; d < 64; d <<= 1) part[o] += __shfl_xor(part[o], d);
  }
  if (lane == 0) {
#pragma unroll
    for (int o = 0; o < 16; ++o) btab[q * 16 + o] = part[o];
  }
}

// bias_m[h][fr][i][nthi] = (16*sigmoid(rpb[h][i][nthi*16+fr]) - 8) * LOG2E
__global__ __launch_bounds__(256)
void bias_exp_k(const float* __restrict__ btab, bf16* __restrict__ bias_m)
{
  int e = blockIdx.x * 256 + threadIdx.x;      // < 131072, 8 nthi per thread
  int h = e >> 13, rem = e & 8191;             // rem: fr(4) i(8) half(1)
  int fr = rem >> 9, i = (rem >> 1) & 255, half = rem & 1;
  bf16x8 o;
#pragma unroll
  for (int jj = 0; jj < 8; ++jj) {
    int nthi = half * 8 + jj;
    int q = ((i >> 4) - nthi + 15) * 31 + ((i & 15) - fr + 15);
    float v = (16.f / (1.f + __expf(-btab[q * 16 + h])) - 8.f) * LOG2E;
    o[jj] = (bf16)v;
  }
  *(bf16x8*)&bias_m[(size_t)e * 8] = o;
}

// ---------------- attention: block = (head hh, window w), 256 thr, 4 Q-chunks
// fixed-shift exp2 softmax; k in 2 halves of 128; LDS 51,968 B -> 3 blocks/CU.
#define KP 36
#define VP 260
#define PP 132
__global__ __launch_bounds__(256)
void attn_k(const bf16* __restrict__ qkv, const bf16* __restrict__ bias_m,
            const float* __restrict__ lsc, bf16* __restrict__ attn_out)
{
  const int hh = blockIdx.x;     // 0..15
  const int w  = blockIdx.y;     // 0..63
  const int tid = threadIdx.x, lane = tid & 63, wave = tid >> 6;
  const int fr = lane & 15, fq = lane >> 4;
  const int r0 = wave * 16;

  __shared__ __align__(16) bf16 Ks[256 * KP];
  __shared__ __align__(16) bf16 Vt[32 * VP];
  __shared__ __align__(16) bf16 Ps[64 * PP];

  const size_t base = (size_t)(w * 256) * 1536;
  const float sc2 = __expf(fminf(lsc[hh], 4.6051701859880914f)) * LOG2E;
  const float shift = sc2 + 12.0f;

#pragma unroll
  for (int i = 0; i < 4; ++i) {
    int c = tid + i * 256;
    int row = c >> 2, d = (c & 3) << 3;
    bf16x8 kv = *(const bf16x8*)&qkv[base + (size_t)row * 1536 + 512 + hh * 32 + d];
    float ss = 0.f;
#pragma unroll
    for (int j = 0; j < 8; ++j) { float f = (float)kv[j]; ss += f * f; }
    ss += __shfl_xor(ss, 1); ss += __shfl_xor(ss, 2);
    float fac = 1.f / fmaxf(sqrtf(ss), 1e-12f);
#pragma unroll
    for (int j = 0; j < 8; ++j) kv[j] = (bf16)((float)kv[j] * fac);
    *(bf16x8*)&Ks[row * KP + d] = kv;
    bf16x8 v = *(const bf16x8*)&qkv[base + (size_t)row * 1536 + 1024 + hh * 32 + d];
#pragma unroll
    for (int j = 0; j < 8; ++j) Vt[(d + j) * VP + row] = v[j];
  }
  __syncthreads();

  const bool vrow = ((w >> 2) & 3) == 3, vcol = (w & 3) == 3;
  const f32x4 zero = {0.f, 0.f, 0.f, 0.f};

  for (int cb = 0; cb < 4; ++cb) {
    bf16x8 aQ = *(const bf16x8*)&qkv[base + (size_t)(cb * 64 + r0 + fr) * 1536 + hh * 32 + fq * 8];
    {
      float ss = 0.f;
#pragma unroll
      for (int j = 0; j < 8; ++j) { float f = (float)aQ[j]; ss += f * f; }
      ss += __shfl_xor(ss, 16); ss += __shfl_xor(ss, 32);
      float fac = sc2 / fmaxf(sqrtf(ss), 1e-12f);
#pragma unroll
      for (int j = 0; j < 8; ++j) aQ[j] = (bf16)((float)aQ[j] * fac);
    }

    float rs[4] = {0.f, 0.f, 0.f, 0.f};
    f32x4 o[2] = {};

#pragma unroll
    for (int kh = 0; kh < 2; ++kh) {
      bf16x8 br[4];
      {
        const bf16* bp = bias_m +
            (size_t)(((hh * 16 + fr) * 256) + cb * 64 + r0 + fq * 4) * 16 + kh * 8;
#pragma unroll
        for (int rr = 0; rr < 4; ++rr) br[rr] = *(const bf16x8*)&bp[rr * 16];
      }

      f32x4 s[8];
#pragma unroll
      for (int nt = 0; nt < 8; ++nt) {
        bf16x8 bK = *(const bf16x8*)&Ks[((kh * 8 + nt) * 16 + fr) * KP + fq * 8];
        s[nt] = MFMA(aQ, bK, zero);
      }

#pragma unroll
      for (int r = 0; r < 4; ++r) {
        int ni = cb * 64 + r0 + fq * 4 + r;
        int ri = ni >> 4, ci = ni & 15;
        bool colm = vcol && ((ci < 8) != (fr < 8));
        bool rowm = vrow && ((ri < 8) != (kh == 0));
        float c = ((colm || rowm) ? -144.2695f : 0.f) - shift;
        float part = 0.f;
#pragma unroll
        for (int nt = 0; nt < 8; ++nt) {
          float p = __builtin_amdgcn_exp2f(s[nt][r] + (float)br[r][nt] + c);
          s[nt][r] = p;
          part += p;
        }
        rs[r] += part;
      }

#pragma unroll
      for (int nt = 0; nt < 8; ++nt)
#pragma unroll
        for (int r = 0; r < 4; ++r)
          Ps[(r0 + fq * 4 + r) * PP + nt * 16 + fr] = (bf16)s[nt][r];

#pragma unroll
      for (int ks = 0; ks < 4; ++ks) {
        bf16x8 aP = *(const bf16x8*)&Ps[(r0 + fr) * PP + ks * 32 + fq * 8];
#pragma unroll
        for (int n2 = 0; n2 < 2; ++n2) {
          bf16x8 bV = *(const bf16x8*)&Vt[(n2 * 16 + fr) * VP + kh * 128 + ks * 32 + fq * 8];
          o[n2] = MFMA(aP, bV, o[n2]);
        }
      }
    }

#pragma unroll
    for (int r = 0; r < 4; ++r) {
      float sum = rs[r];
      sum += __shfl_xor(sum, 1); sum += __shfl_xor(sum, 2);
      sum += __shfl_xor(sum, 4); sum += __shfl_xor(sum, 8);
      float inv = __builtin_amdgcn_rcpf(sum);
      int ni = cb * 64 + r0 + fq * 4 + r;
#pragma unroll
      for (int n2 = 0; n2 < 2; ++n2)
        attn_out[((size_t)(w * 256 + ni)) * 512 + hh * 32 + n2 * 16 + fr] =
            (bf16)(o[n2][r] * inv);
    }
  }
}

// ---------------- LayerNorm + residual: out = res(bf16) + LN(vin)
template<int MODE>
__global__ __launch_bounds__(256)
void ln_res_k(const bf16* __restrict__ vin, const bf16* __restrict__ res,
              const float* __restrict__ gam, const float* __restrict__ bet,
              bf16* __restrict__ outb, float* __restrict__ outf)
{
  const int row = blockIdx.x * 4 + (threadIdx.x >> 6);
  const int lane = threadIdx.x & 63;
  const size_t base = (size_t)row * 512 + lane * 8;
  bf16x8 inv = *(const bf16x8*)(vin + base);
  float v[8];
#pragma unroll
  for (int j = 0; j < 8; ++j) v[j] = (float)inv[j];
  float s = 0.f, s2 = 0.f;
#pragma unroll
  for (int j = 0; j < 8; ++j) { s += v[j]; s2 += v[j] * v[j]; }
#pragma unroll
  for (int d = 1; d < 64; d <<= 1) { s += __shfl_xor(s, d); s2 += __shfl_xor(s2, d); }
  float mean = s * (1.f / 512.f);
  float var = s2 * (1.f / 512.f) - mean * mean;
  float rstd = rsqrtf(var + 1e-5f);

  bf16x8 r8 = *(const bf16x8*)(res + base);
  f32x4 g1 = *(const f32x4*)(gam + lane * 8);
  f32x4 g2 = *(const f32x4*)(gam + lane * 8 + 4);
  f32x4 b1 = *(const f32x4*)(bet + lane * 8);
  f32x4 b2 = *(const f32x4*)(bet + lane * 8 + 4);

  bf16x8 ob;
  f32x4 o1, o2;
#pragma unroll
  for (int j = 0; j < 8; ++j) {
    float g = (j < 4) ? g1[j] : g2[j - 4];
    float b = (j < 4) ? b1[j] : b2[j - 4];
    float ln = (v[j] - mean) * rstd * g + b;
    float ov = (float)r8[j] + ln;
    if (MODE == 0) ob[j] = (bf16)ov;
    else { if (j < 4) o1[j] = ov; else o2[j - 4] = ov; }
  }
  if (MODE == 0) *(bf16x8*)(outb + base) = ob;
  else { *(f32x4*)(outf + base) = o1; *(f32x4*)(outf + base + 4) = o2; }
}

// ---------------- launch
extern "C" void kernel_launch(void* const* d_in, const int* in_sizes, int n_in,
                              void* d_out, int out_size, void* d_ws, size_t ws_size,
                              hipStream_t stream) {
  const float* x    = (const float*)d_in[0];
  const float* n1g  = (const float*)d_in[3];
  const float* n1b  = (const float*)d_in[4];
  const float* qkvw = (const float*)d_in[5];
  const float* qb   = (const float*)d_in[6];
  const float* vb   = (const float*)d_in[7];
  const float* lsc  = (const float*)d_in[8];
  const float* cw1  = (const float*)d_in[9];
  const float* cb1  = (const float*)d_in[10];
  const float* cw2  = (const float*)d_in[11];
  const float* pw   = (const float*)d_in[12];
  const float* pb   = (const float*)d_in[13];
  const float* n2g  = (const float*)d_in[14];
  const float* n2b  = (const float*)d_in[15];
  const float* f1w  = (const float*)d_in[16];
  const float* f1b  = (const float*)d_in[17];
  const float* f2w  = (const float*)d_in[18];
  const float* f2b  = (const float*)d_in[19];

  // workspace layout (bytes), peak 75,563,008 (proven rounds 4-10):
  //   weights/bias @0..8,454,144
  //   xb    @8,454,144  (16.8M) [start -> LN1];  h1 reuses @8,454,144 (33.55M)
  //   qkv_t @25,231,360 (50.3M) [QKV -> attn];  projo reuses (16.8M)
  //   x1b   @42,008,576 (16.8M) [LN1 -> final]
  //   m_buf @58,785,792 (16.8M) [FC2 -> final]
  // d_out: attn_o (16.8M), then h0 (33.5M), then final f32 out.
  char* ws = (char*)d_ws;
  bf16*  qkvw_b = (bf16*)(ws);
  bf16*  pw_b   = (bf16*)(ws + 1572864);
  bf16*  f1w_b  = (bf16*)(ws + 2097152);
  bf16*  f2w_b  = (bf16*)(ws + 4194304);
  float* btab   = (float*)(ws + 6291456);
  bf16*  bias_m = (bf16*)(ws + 6356992);
  bf16*  xb     = (bf16*)(ws + 8454144);
  bf16*  h1     = (bf16*)(ws + 8454144);
  bf16*  qkv_t  = (bf16*)(ws + 25231360);
  bf16*  projo  = (bf16*)(ws + 25231360);
  bf16*  x1b    = (bf16*)(ws + 42008576);
  bf16*  m_buf  = (bf16*)(ws + 58785792);
  bf16*  attn_o = (bf16*)d_out;
  bf16*  h0     = (bf16*)d_out;

  f2b_all_k<<<5632, 256, 0, stream>>>(x, qkvw, pw, f1w, f2w,
                                      xb, qkvw_b, pw_b, f1w_b, f2w_b);
  cpb_tbl_k<<<961, 64, 0, stream>>>(cw1, cb1, cw2, btab);
  bias_exp_k<<<512, 256, 0, stream>>>(btab, bias_m);

  gemm3_k<0, 256><<<dim3(64, 6), 512, 0, stream>>>(xb, nullptr, qkvw_b, qb, vb, qkv_t, nullptr, 512, 512, 512, 1536);
  attn_k<<<dim3(16, 64), 256, 0, stream>>>(qkv_t, bias_m, lsc, attn_o);
  gemm3_k<1, 128><<<dim3(64, 4), 512, 0, stream>>>(attn_o, nullptr, pw_b, pb, nullptr, projo, nullptr, 512, 512, 512, 512);
  ln_res_k<0><<<4096, 256, 0, stream>>>(projo, xb, n1g, n1b, x1b, nullptr);
  gemm3_k<2, 256><<<dim3(64, 8), 512, 0, stream>>>(x1b, nullptr, f1w_b, f1b, nullptr, h0, h1, 512, 512, 512, 1024);
  gemm3_k<3, 128><<<dim3(64, 4), 512, 0, stream>>>(h0, h1, f2w_b, f2b, nullptr, m_buf, nullptr, 2048, 1024, 2048, 512);
  ln_res_k<1><<<4096, 256, 0, stream>>>(m_buf, x1b, n2g, n2b, nullptr, (float*)d_out);
}

// Round 14
// 229.154 us; speedup vs baseline: 1.1269x; 1.1269x over previous
//
#include <hip/hip_runtime.h>

typedef __bf16 bf16;
typedef __bf16 bf16x8 __attribute__((ext_vector_type(8)));
typedef float  f32x4  __attribute__((ext_vector_type(4)));

#define MFMA(a, b, c) __builtin_amdgcn_mfma_f32_16x16x32_bf16((a), (b), (c), 0, 0, 0)
#define LOG2E 1.4426950408889634f

__device__ __forceinline__ void gload16(const bf16* g, bf16* l) {
  __builtin_amdgcn_global_load_lds(
      (const __attribute__((address_space(1))) unsigned int*)g,
      (__attribute__((address_space(3))) unsigned int*)l, 16, 0, 0);
}

// fast GELU: x * e/(e+1), e = exp2(2*log2e*(0.79788456x + 0.0356774x^3))
__device__ __forceinline__ float gelu_f(float v) {
  float u = v * (0.7978845608f + 0.0356774081f * v * v);
  float t2 = fminf(u * (2.f * LOG2E), 126.f);
  float e = __builtin_amdgcn_exp2f(t2);
  return v * e * __builtin_amdgcn_rcpf(e + 1.f);
}

// ---------------- fused f32 -> bf16 convert for x + 4 weight tensors
__global__ __launch_bounds__(256)
void f2b_all_k(const float* __restrict__ x, const float* __restrict__ qkvw,
               const float* __restrict__ pw, const float* __restrict__ f1w,
               const float* __restrict__ f2w,
               bf16* __restrict__ xb, bf16* __restrict__ qkvwb,
               bf16* __restrict__ pwb, bf16* __restrict__ f1wb,
               bf16* __restrict__ f2wb)
{
  int i = blockIdx.x * 256 + threadIdx.x;   // 8-elem chunk index
  const float* in; bf16* out; int base;
  if      (i < 1048576) { in = x;    out = xb;    base = 0; }
  else if (i < 1146880) { in = qkvw; out = qkvwb; base = 1048576; }
  else if (i < 1179648) { in = pw;   out = pwb;   base = 1146880; }
  else if (i < 1310720) { in = f1w;  out = f1wb;  base = 1179648; }
  else if (i < 1441792) { in = f2w;  out = f2wb;  base = 1310720; }
  else return;
  size_t j = (size_t)(i - base) * 8;
  f32x4 a = *(const f32x4*)(in + j);
  f32x4 b = *(const f32x4*)(in + j + 4);
  bf16x8 o;
#pragma unroll
  for (int k = 0; k < 4; ++k) { o[k] = (bf16)a[k]; o[4 + k] = (bf16)b[k]; }
  *(bf16x8*)(out + j) = o;
}

// shifted-window token t = w*256+n  ->  natural token index (b*4096 + gh*64 + gw)
__device__ __forceinline__ int row_map(int t) {
  int w = t >> 8, n = t & 255;
  int b = w >> 4, wi = w & 15;
  int gh = (((wi >> 2) << 4) + (n >> 4) + 8) & 63;
  int gw = (((wi & 3) << 4) + (n & 15) + 8) & 63;
  return (b << 12) + (gh << 6) + gw;
}

// ---------------- GEMM v2 (r10-proven) + bijective XCD block swizzle.
// 128x128 tile, BK=64, 512 thr (8 waves 2Mx4N); T3-minimum loop: stage(t+1)
// at tile top, compute(t) with setprio'd MFMA, ONE fused vmcnt(0)+barrier
// per tile. XOR-swizzled LDS (pre-swizzled source, linear dest, swz read).
// Swizzle: work linearized x-SLOWEST (bx*gy+by) so each XCD's contiguous
// chunk shares A-row panels across n0 tiles (A read 4-16x per GEMM).
// MODE 0: QKV  (A row-gather via row_map, bias=concat(qb,0,vb))
// MODE 1: PROJ (bias, out rows scattered via row_map)
// MODE 2: FC1  (bias + fast GELU, out split h0/h1 by column half)
// MODE 3: FC2  (bias, A split h0/h1 by k half, K=2048)
template<int MODE>
__global__ __launch_bounds__(512)
void gemm2_k(const bf16* __restrict__ A0, const bf16* __restrict__ A1,
             const bf16* __restrict__ W,
             const float* __restrict__ b0, const float* __restrict__ b1,
             bf16* __restrict__ out0, bf16* __restrict__ out1,
             int K, int lda, int ldw, int ldc)
{
  __shared__ __align__(16) bf16 As[2][128 * 64];   // 32 KB
  __shared__ __align__(16) bf16 Bs[2][128 * 64];   // 32 KB
  const int tid  = threadIdx.x;
  const int lane = tid & 63;
  const int wave = tid >> 6;
  const int wm = wave >> 2, wn = wave & 3;         // 2 x 4 waves
  const int fr = lane & 15, fq = lane >> 4;

  // XCD-aware bijective swizzle (all grids: nwg % 8 == 0)
  const int gx = gridDim.x, gy = gridDim.y;
  int id = blockIdx.y * gx + blockIdx.x;
  const int q8 = (gx * gy) >> 3;
  int sw = (id & 7) * q8 + (id >> 3);
  const int m0 = (sw / gy) * 128;
  const int n0 = (sw % gy) * 128;

  f32x4 acc[4][2] = {};

  auto stage = [&](int buf, int t) {
    const int kb = t << 6;
#pragma unroll
    for (int i = 0; i < 2; ++i) {
      int c = tid + i * 512;                 // chunk 0..1023 (16B each)
      int row = c >> 3, sl = c & 7;
      int kk = ((sl ^ (row & 7)) << 3);      // swizzled source slot
      int arow = m0 + row;
      if (MODE == 0) arow = row_map(arow);
      const bf16* ap;
      if (MODE == 3) {
        const bf16* Ab = (kb < 1024) ? A0 : A1;
        ap = Ab + (size_t)arow * lda + (kb & 1023) + kk;
      } else {
        ap = A0 + (size_t)arow * lda + kb + kk;
      }
      gload16(ap, &As[buf][c * 8]);
      gload16(W + (size_t)(n0 + row) * ldw + kb + kk, &Bs[buf][c * 8]);
    }
  };

  const int nt = K >> 6;
  stage(0, 0);
  asm volatile("s_waitcnt vmcnt(0)" ::: "memory");
  __builtin_amdgcn_s_barrier();
  for (int t = 0; t < nt; ++t) {
    if (t + 1 < nt) stage((t + 1) & 1, t + 1);     // into OTHER buffer; flies all tile
    const bf16* as = As[t & 1];
    const bf16* bs = Bs[t & 1];
#pragma unroll
    for (int k2 = 0; k2 < 2; ++k2) {
      const int sw2 = ((k2 * 4 + fq) ^ (fr & 7)) << 3;
      bf16x8 bF[2];
#pragma unroll
      for (int n = 0; n < 2; ++n)
        bF[n] = *(const bf16x8*)&bs[(wn * 32 + n * 16 + fr) * 64 + sw2];
      bf16x8 aF[4];
#pragma unroll
      for (int m = 0; m < 4; ++m)
        aF[m] = *(const bf16x8*)&as[(wm * 64 + m * 16 + fr) * 64 + sw2];
      __builtin_amdgcn_s_setprio(1);
#pragma unroll
      for (int m = 0; m < 4; ++m)
#pragma unroll
        for (int n = 0; n < 2; ++n)
          acc[m][n] = MFMA(aF[m], bF[n], acc[m][n]);
      __builtin_amdgcn_s_setprio(0);
    }
    if (t + 1 < nt) {
      asm volatile("s_waitcnt vmcnt(0)" ::: "memory");  // t+1's loads landed
      __builtin_amdgcn_s_barrier();                     // all waves: reads done, data in
    }
  }

#pragma unroll
  for (int m = 0; m < 4; ++m) {
#pragma unroll
    for (int n = 0; n < 2; ++n) {
      int colb = n0 + wn * 32 + n * 16 + fr;
      float badd;
      if (MODE == 0)
        badd = (colb < 512) ? b0[colb] : (colb < 1024 ? 0.f : b1[colb - 1024]);
      else
        badd = b0[colb];
#pragma unroll
      for (int r = 0; r < 4; ++r) {
        int rowb = m0 + wm * 64 + m * 16 + fq * 4 + r;
        float v = acc[m][n][r] + badd;
        if (MODE == 0) out0[(size_t)rowb * ldc + colb] = (bf16)v;
        if (MODE == 1) out0[(size_t)row_map(rowb) * ldc + colb] = (bf16)v;
        if (MODE == 2) {
          v = gelu_f(v);
          bf16* ob = (colb < 1024) ? out0 : out1;
          ob[(size_t)rowb * 1024 + (colb & 1023)] = (bf16)v;
        }
        if (MODE == 3) out0[(size_t)rowb * ldc + colb] = (bf16)v;
      }
    }
  }
}

// ---------------- CPB MLP: btab[q][16], q = (dr+15)*31 + (dc+15)
__device__ __forceinline__ float cpb_coord(int r) {
  float t = (float)r * (8.0f / 15.0f);
  float v = log2f(fabsf(t) + 1.0f) * (1.0f / 3.0f);
  return (t < 0.0f) ? -v : v;
}

__global__ __launch_bounds__(64)
void cpb_tbl_k(const float* __restrict__ w1, const float* __restrict__ b1,
               const float* __restrict__ w2, float* __restrict__ btab)
{
  const int q = blockIdx.x;           // 0..960
  const int lane = threadIdx.x;       // 64
  const float t0 = cpb_coord(q / 31 - 15);
  const float t1 = cpb_coord(q % 31 - 15);
  float part[16];
#pragma unroll
  for (int o = 0; o < 16; ++o) part[o] = 0.f;
  for (int jj = 0; jj < 8; ++jj) {
    int j = lane * 8 + jj;
    float hv = t0 * w1[j * 2] + t1 * w1[j * 2 + 1] + b1[j];
    hv = fmaxf(hv, 0.f);
#pragma unroll
    for (int o = 0; o < 16; ++o) part[o] += hv * w2[o * 512 + j];
  }
#pragma unroll
  for (int o = 0; o < 16; ++o) {
#pragma unroll
    for (int d = 1; d < 64; d <<= 1) part[o] += __shfl_xor(part[o], d);
  }
  if (lane == 0) {
#pragma unroll
    for (int o = 0; o < 16; ++o) btab[q * 16 + o] = part[o];
  }
}

// bias_m[h][fr][i][nthi] = (16*sigmoid(rpb[h][i][nthi*16+fr]) - 8) * LOG2E
__global__ __launch_bounds__(256)
void bias_exp_k(const float* __restrict__ btab, bf16* __restrict__ bias_m)
{
  int e = blockIdx.x * 256 + threadIdx.x;      // < 131072, 8 nthi per thread
  int h = e >> 13, rem = e & 8191;             // rem: fr(4) i(8) half(1)
  int fr = rem >> 9, i = (rem >> 1) & 255, half = rem & 1;
  bf16x8 o;
#pragma unroll
  for (int jj = 0; jj < 8; ++jj) {
    int nthi = half * 8 + jj;
    int q = ((i >> 4) - nthi + 15) * 31 + ((i & 15) - fr + 15);
    float v = (16.f / (1.f + __expf(-btab[q * 16 + h])) - 8.f) * LOG2E;
    o[jj] = (bf16)v;
  }
  *(bf16x8*)&bias_m[(size_t)e * 8] = o;
}

// ---------------- attention: block = (head hh, window w), 256 thr, 4 Q-chunks
// fixed-shift exp2 softmax; k in 2 halves of 128; LDS 51,968 B -> 3 blocks/CU.
#define KP 36
#define VP 260
#define PP 132
__global__ __launch_bounds__(256)
void attn_k(const bf16* __restrict__ qkv, const bf16* __restrict__ bias_m,
            const float* __restrict__ lsc, bf16* __restrict__ attn_out)
{
  const int hh = blockIdx.x;     // 0..15
  const int w  = blockIdx.y;     // 0..63
  const int tid = threadIdx.x, lane = tid & 63, wave = tid >> 6;
  const int fr = lane & 15, fq = lane >> 4;
  const int r0 = wave * 16;

  __shared__ __align__(16) bf16 Ks[256 * KP];
  __shared__ __align__(16) bf16 Vt[32 * VP];
  __shared__ __align__(16) bf16 Ps[64 * PP];

  const size_t base = (size_t)(w * 256) * 1536;
  const float sc2 = __expf(fminf(lsc[hh], 4.6051701859880914f)) * LOG2E;
  const float shift = sc2 + 12.0f;

#pragma unroll
  for (int i = 0; i < 4; ++i) {
    int c = tid + i * 256;
    int row = c >> 2, d = (c & 3) << 3;
    bf16x8 kv = *(const bf16x8*)&qkv[base + (size_t)row * 1536 + 512 + hh * 32 + d];
    float ss = 0.f;
#pragma unroll
    for (int j = 0; j < 8; ++j) { float f = (float)kv[j]; ss += f * f; }
    ss += __shfl_xor(ss, 1); ss += __shfl_xor(ss, 2);
    float fac = 1.f / fmaxf(sqrtf(ss), 1e-12f);
#pragma unroll
    for (int j = 0; j < 8; ++j) kv[j] = (bf16)((float)kv[j] * fac);
    *(bf16x8*)&Ks[row * KP + d] = kv;
    bf16x8 v = *(const bf16x8*)&qkv[base + (size_t)row * 1536 + 1024 + hh * 32 + d];
#pragma unroll
    for (int j = 0; j < 8; ++j) Vt[(d + j) * VP + row] = v[j];
  }
  __syncthreads();

  const bool vrow = ((w >> 2) & 3) == 3, vcol = (w & 3) == 3;
  const f32x4 zero = {0.f, 0.f, 0.f, 0.f};

  for (int cb = 0; cb < 4; ++cb) {
    bf16x8 aQ = *(const bf16x8*)&qkv[base + (size_t)(cb * 64 + r0 + fr) * 1536 + hh * 32 + fq * 8];
    {
      float ss = 0.f;
#pragma unroll
      for (int j = 0; j < 8; ++j) { float f = (float)aQ[j]; ss += f * f; }
      ss += __shfl_xor(ss, 16); ss += __shfl_xor(ss, 32);
      float fac = sc2 / fmaxf(sqrtf(ss), 1e-12f);
#pragma unroll
      for (int j = 0; j < 8; ++j) aQ[j] = (bf16)((float)aQ[j] * fac);
    }

    float rs[4] = {0.f, 0.f, 0.f, 0.f};
    f32x4 o[2] = {};

#pragma unroll
    for (int kh = 0; kh < 2; ++kh) {
      bf16x8 br[4];
      {
        const bf16* bp = bias_m +
            (size_t)(((hh * 16 + fr) * 256) + cb * 64 + r0 + fq * 4) * 16 + kh * 8;
#pragma unroll
        for (int rr = 0; rr < 4; ++rr) br[rr] = *(const bf16x8*)&bp[rr * 16];
      }

      f32x4 s[8];
#pragma unroll
      for (int nt = 0; nt < 8; ++nt) {
        bf16x8 bK = *(const bf16x8*)&Ks[((kh * 8 + nt) * 16 + fr) * KP + fq * 8];
        s[nt] = MFMA(aQ, bK, zero);
      }

#pragma unroll
      for (int r = 0; r < 4; ++r) {
        int ni = cb * 64 + r0 + fq * 4 + r;
        int ri = ni >> 4, ci = ni & 15;
        bool colm = vcol && ((ci < 8) != (fr < 8));
        bool rowm = vrow && ((ri < 8) != (kh == 0));
        float c = ((colm || rowm) ? -144.2695f : 0.f) - shift;
        float part = 0.f;
#pragma unroll
        for (int nt = 0; nt < 8; ++nt) {
          float p = __builtin_amdgcn_exp2f(s[nt][r] + (float)br[r][nt] + c);
          s[nt][r] = p;
          part += p;
        }
        rs[r] += part;
      }

#pragma unroll
      for (int nt = 0; nt < 8; ++nt)
#pragma unroll
        for (int r = 0; r < 4; ++r)
          Ps[(r0 + fq * 4 + r) * PP + nt * 16 + fr] = (bf16)s[nt][r];

#pragma unroll
      for (int ks = 0; ks < 4; ++ks) {
        bf16x8 aP = *(const bf16x8*)&Ps[(r0 + fr) * PP + ks * 32 + fq * 8];
#pragma unroll
        for (int n2 = 0; n2 < 2; ++n2) {
          bf16x8 bV = *(const bf16x8*)&Vt[(n2 * 16 + fr) * VP + kh * 128 + ks * 32 + fq * 8];
          o[n2] = MFMA(aP, bV, o[n2]);
        }
      }
    }

#pragma unroll
    for (int r = 0; r < 4; ++r) {
      float sum = rs[r];
      sum += __shfl_xor(sum, 1); sum += __shfl_xor(sum, 2);
      sum += __shfl_xor(sum, 4); sum += __shfl_xor(sum, 8);
      float inv = __builtin_amdgcn_rcpf(sum);
      int ni = cb * 64 + r0 + fq * 4 + r;
#pragma unroll
      for (int n2 = 0; n2 < 2; ++n2)
        attn_out[((size_t)(w * 256 + ni)) * 512 + hh * 32 + n2 * 16 + fr] =
            (bf16)(o[n2][r] * inv);
    }
  }
}

// ---------------- LayerNorm + residual: out = res(bf16) + LN(vin)
template<int MODE>
__global__ __launch_bounds__(256)
void ln_res_k(const bf16* __restrict__ vin, const bf16* __restrict__ res,
              const float* __restrict__ gam, const float* __restrict__ bet,
              bf16* __restrict__ outb, float* __restrict__ outf)
{
  const int row = blockIdx.x * 4 + (threadIdx.x >> 6);
  const int lane = threadIdx.x & 63;
  const size_t base = (size_t)row * 512 + lane * 8;
  bf16x8 inv = *(const bf16x8*)(vin + base);
  float v[8];
#pragma unroll
  for (int j = 0; j < 8; ++j) v[j] = (float)inv[j];
  float s = 0.f, s2 = 0.f;
#pragma unroll
  for (int j = 0; j < 8; ++j) { s += v[j]; s2 += v[j] * v[j]; }
#pragma unroll
  for (int d = 1; d < 64; d <<= 1) { s += __shfl_xor(s, d); s2 += __shfl_xor(s2, d); }
  float mean = s * (1.f / 512.f);
  float var = s2 * (1.f / 512.f) - mean * mean;
  float rstd = rsqrtf(var + 1e-5f);

  bf16x8 r8 = *(const bf16x8*)(res + base);
  f32x4 g1 = *(const f32x4*)(gam + lane * 8);
  f32x4 g2 = *(const f32x4*)(gam + lane * 8 + 4);
  f32x4 b1 = *(const f32x4*)(bet + lane * 8);
  f32x4 b2 = *(const f32x4*)(bet + lane * 8 + 4);

  bf16x8 ob;
  f32x4 o1, o2;
#pragma unroll
  for (int j = 0; j < 8; ++j) {
    float g = (j < 4) ? g1[j] : g2[j - 4];
    float b = (j < 4) ? b1[j] : b2[j - 4];
    float ln = (v[j] - mean) * rstd * g + b;
    float ov = (float)r8[j] + ln;
    if (MODE == 0) ob[j] = (bf16)ov;
    else { if (j < 4) o1[j] = ov; else o2[j - 4] = ov; }
  }
  if (MODE == 0) *(bf16x8*)(outb + base) = ob;
  else { *(f32x4*)(outf + base) = o1; *(f32x4*)(outf + base + 4) = o2; }
}

// ---------------- launch
extern "C" void kernel_launch(void* const* d_in, const int* in_sizes, int n_in,
                              void* d_out, int out_size, void* d_ws, size_t ws_size,
                              hipStream_t stream) {
  const float* x    = (const float*)d_in[0];
  const float* n1g  = (const float*)d_in[3];
  const float* n1b  = (const float*)d_in[4];
  const float* qkvw = (const float*)d_in[5];
  const float* qb   = (const float*)d_in[6];
  const float* vb   = (const float*)d_in[7];
  const float* lsc  = (const float*)d_in[8];
  const float* cw1  = (const float*)d_in[9];
  const float* cb1  = (const float*)d_in[10];
  const float* cw2  = (const float*)d_in[11];
  const float* pw   = (const float*)d_in[12];
  const float* pb   = (const float*)d_in[13];
  const float* n2g  = (const float*)d_in[14];
  const float* n2b  = (const float*)d_in[15];
  const float* f1w  = (const float*)d_in[16];
  const float* f1b  = (const float*)d_in[17];
  const float* f2w  = (const float*)d_in[18];
  const float* f2b  = (const float*)d_in[19];

  // workspace layout (bytes), peak 75,563,008 (proven rounds 4-13):
  //   weights/bias @0..8,454,144
  //   xb    @8,454,144  (16.8M) [start -> LN1];  h1 reuses @8,454,144 (33.55M)
  //   qkv_t @25,231,360 (50.3M) [QKV -> attn];  projo reuses (16.8M)
  //   x1b   @42,008,576 (16.8M) [LN1 -> final]
  //   m_buf @58,785,792 (16.8M) [FC2 -> final]
  // d_out: attn_o (16.8M), then h0 (33.5M), then final f32 out.
  char* ws = (char*)d_ws;
  bf16*  qkvw_b = (bf16*)(ws);
  bf16*  pw_b   = (bf16*)(ws + 1572864);
  bf16*  f1w_b  = (bf16*)(ws + 2097152);
  bf16*  f2w_b  = (bf16*)(ws + 4194304);
  float* btab   = (float*)(ws + 6291456);
  bf16*  bias_m = (bf16*)(ws + 6356992);
  bf16*  xb     = (bf16*)(ws + 8454144);
  bf16*  h1     = (bf16*)(ws + 8454144);
  bf16*  qkv_t  = (bf16*)(ws + 25231360);
  bf16*  projo  = (bf16*)(ws + 25231360);
  bf16*  x1b    = (bf16*)(ws + 42008576);
  bf16*  m_buf  = (bf16*)(ws + 58785792);
  bf16*  attn_o = (bf16*)d_out;
  bf16*  h0     = (bf16*)d_out;

  f2b_all_k<<<5632, 256, 0, stream>>>(x, qkvw, pw, f1w, f2w,
                                      xb, qkvw_b, pw_b, f1w_b, f2w_b);
  cpb_tbl_k<<<961, 64, 0, stream>>>(cw1, cb1, cw2, btab);
  bias_exp_k<<<512, 256, 0, stream>>>(btab, bias_m);

  gemm2_k<0><<<dim3(128, 12), 512, 0, stream>>>(xb, nullptr, qkvw_b, qb, vb, qkv_t, nullptr, 512, 512, 512, 1536);
  attn_k<<<dim3(16, 64), 256, 0, stream>>>(qkv_t, bias_m, lsc, attn_o);
  gemm2_k<1><<<dim3(128, 4), 512, 0, stream>>>(attn_o, nullptr, pw_b, pb, nullptr, projo, nullptr, 512, 512, 512, 512);
  ln_res_k<0><<<4096, 256, 0, stream>>>(projo, xb, n1g, n1b, x1b, nullptr);
  gemm2_k<2><<<dim3(128, 16), 512, 0, stream>>>(x1b, nullptr, f1w_b, f1b, nullptr, h0, h1, 512, 512, 512, 1024);
  gemm2_k<3><<<dim3(128, 4), 512, 0, stream>>>(h0, h1, f2w_b, f2b, nullptr, m_buf, nullptr, 2048, 1024, 2048, 512);
  ln_res_k<1><<<4096, 256, 0, stream>>>(m_buf, x1b, n2g, n2b, nullptr, (float*)d_out);
}